// Round 1
// baseline (3234.346 us; speedup 1.0000x reference)
//
#include <hip/hip_runtime.h>

typedef unsigned short u16;
typedef __attribute__((ext_vector_type(8))) short   short8;
typedef __attribute__((ext_vector_type(4))) float   f32x4;
typedef __attribute__((ext_vector_type(4))) u16     u16x4;
typedef __attribute__((ext_vector_type(8))) u16     u16x8;

__device__ __forceinline__ u16 f2bf(float f) {
  unsigned u = __float_as_uint(f);
  u += 0x7FFFu + ((u >> 16) & 1u);   // RNE
  return (u16)(u >> 16);
}
__device__ __forceinline__ float bf2f(u16 h) { return __uint_as_float(((unsigned)h) << 16); }
__device__ __forceinline__ float lrelu(float v) { return v > 0.f ? v : 0.01f * v; }

// LDS layout (bytes), total exactly 64 KiB -> 2 blocks/CU
#define LDS_D  0       // 64 edges x 64  bf16 = 8192
#define LDS_H1 8192    // 64 x 256 bf16 = 32768
#define LDS_H2 40960   // 64 x 128 bf16 = 16384
#define LDS_H3 57344   // 64 x 64  bf16 = 8192

// D = W(A: MxK) * act(B: KxN=64 edges). Fragments:
//   A lane: row=lane&15 (out-ch), k = ks + (lane>>4)*8 .. +8   (contig 16B global)
//   B lane: col=lane&15 (edge),  k same                         (contig 16B LDS, XOR-swizzled)
//   D lane: col=lane&15 (edge),  rows (lane>>4)*4 + 0..3        (packed 8B LDS write)
template<int K, int MW>
__device__ __forceinline__ void gemm_layer(
    const u16* __restrict__ w, const float* __restrict__ bias,
    const char* lin, int in_stride, char* lout, int out_stride,
    int wave, int lane)
{
  const int r = lane & 15, g = lane >> 4;
  f32x4 acc[MW][4] = {};
  const int m0 = wave * (MW * 16);
#pragma unroll
  for (int ks = 0; ks < K; ks += 32) {
    const int kk = ks + g * 8;
    short8 a[MW], b[4];
#pragma unroll
    for (int mw = 0; mw < MW; mw++)
      a[mw] = *(const short8*)(w + (size_t)(m0 + mw * 16 + r) * K + kk);
#pragma unroll
    for (int nt = 0; nt < 4; nt++) {
      const int ed = nt * 16 + r;
      const unsigned byt = ((unsigned)(ed * in_stride + kk * 2)) ^ ((unsigned)(ed & 7) << 4);
      b[nt] = *(const short8*)(lin + byt);
    }
#pragma unroll
    for (int mw = 0; mw < MW; mw++)
#pragma unroll
      for (int nt = 0; nt < 4; nt++)
        acc[mw][nt] = __builtin_amdgcn_mfma_f32_16x16x32_bf16(a[mw], b[nt], acc[mw][nt], 0, 0, 0);
  }
  const int row0 = g * 4;
#pragma unroll
  for (int mw = 0; mw < MW; mw++) {
    const int mrow = m0 + mw * 16 + row0;
    const float bb0 = bias[mrow + 0], bb1 = bias[mrow + 1];
    const float bb2 = bias[mrow + 2], bb3 = bias[mrow + 3];
#pragma unroll
    for (int nt = 0; nt < 4; nt++) {
      const int ed = nt * 16 + r;
      u16x4 pk;
      pk[0] = f2bf(lrelu(acc[mw][nt][0] + bb0));
      pk[1] = f2bf(lrelu(acc[mw][nt][1] + bb1));
      pk[2] = f2bf(lrelu(acc[mw][nt][2] + bb2));
      pk[3] = f2bf(lrelu(acc[mw][nt][3] + bb3));
      const unsigned byt = ((unsigned)(ed * out_stride + mrow * 2)) ^ ((unsigned)(ed & 7) << 4);
      *(u16x4*)(lout + byt) = pk;
    }
  }
}

__global__ __launch_bounds__(256, 2) void edge_mlp(
    const float* __restrict__ x, const int* __restrict__ src, const int* __restrict__ dst,
    const u16* __restrict__ w1b, const u16* __restrict__ w2b, const u16* __restrict__ w3b,
    const float* __restrict__ b1, const float* __restrict__ b2, const float* __restrict__ b3,
    const float* __restrict__ w4, const float* __restrict__ b4,
    float* __restrict__ sacc, float* __restrict__ deg, float* __restrict__ eout, int E)
{
  __shared__ char lds[65536];
  const int tid = threadIdx.x;
  const int wave = tid >> 6, lane = tid & 63;
  const long e0 = (long)blockIdx.x * 64;

  // -------- gather d = x[src] - x[dst] into LDS (bf16, XOR-swizzled) --------
  {
    const int et = tid >> 2, part = tid & 3;
    long e = e0 + et;
    long ec = e < E ? e : (long)E - 1;
    const int sn = src[ec], dn = dst[ec];
    const float4* xs = (const float4*)(x + (size_t)sn * 64 + part * 16);
    const float4* xd = (const float4*)(x + (size_t)dn * 64 + part * 16);
    u16x8 ov[2];
#pragma unroll
    for (int c = 0; c < 4; c++) {
      float4 a = xs[c], bq = xd[c];
      ov[c >> 1][(c & 1) * 4 + 0] = f2bf(a.x - bq.x);
      ov[c >> 1][(c & 1) * 4 + 1] = f2bf(a.y - bq.y);
      ov[c >> 1][(c & 1) * 4 + 2] = f2bf(a.z - bq.z);
      ov[c >> 1][(c & 1) * 4 + 3] = f2bf(a.w - bq.w);
    }
    const unsigned base = (unsigned)(et * 128 + part * 32);
    const unsigned sw = (unsigned)(et & 7) << 4;
    *(u16x8*)(lds + LDS_D + (base ^ sw)) = ov[0];
    *(u16x8*)(lds + LDS_D + ((base + 16) ^ sw)) = ov[1];
  }
  __syncthreads();

  // -------- MLP chain on MFMA --------
  gemm_layer<64, 4>(w1b, b1, lds + LDS_D, 128, lds + LDS_H1, 512, wave, lane);
  __syncthreads();
  gemm_layer<256, 2>(w2b, b2, lds + LDS_H1, 512, lds + LDS_H2, 256, wave, lane);
  __syncthreads();
  gemm_layer<128, 1>(w3b, b3, lds + LDS_H2, 256, lds + LDS_H3, 128, wave, lane);
  __syncthreads();

  // -------- layer 4 (dot with w4) + sigmoid; wave 0 only --------
  float* e_sh = (float*)lds;  // reuse dead d-tile region
  if (tid < 64) {
    const long e = e0 + tid;
    float sum = b4[0];
    const unsigned sw = (unsigned)(tid & 7) << 4;
#pragma unroll
    for (int kc = 0; kc < 64; kc += 8) {
      u16x8 hv = *(const u16x8*)(lds + LDS_H3 + (((unsigned)(tid * 128 + kc * 2)) ^ sw));
#pragma unroll
      for (int j = 0; j < 8; j++) sum += bf2f(hv[j]) * w4[kc + j];
    }
    const float ev = 1.f / (1.f + __expf(-sum));
    if (e < E) {
      eout[e] = ev;
      e_sh[tid] = ev;
      atomicAdd(&deg[dst[e]], 1.0f);
    } else {
      e_sh[tid] = 0.f;
    }
  }
  __syncthreads();

  // -------- scatter msg = e * x[src] into sacc (fp32 atomics) --------
  {
    const int et = tid >> 2, part = tid & 3;
    const long e = e0 + et;
    if (e < E) {
      const float ev = e_sh[et];
      const int sn = src[e], dn = dst[e];
      const float4* xs = (const float4*)(x + (size_t)sn * 64 + part * 16);
      float* sp = sacc + (size_t)dn * 64 + part * 16;
#pragma unroll
      for (int c = 0; c < 4; c++) {
        float4 v = xs[c];
        atomicAdd(sp + c * 4 + 0, v.x * ev);
        atomicAdd(sp + c * 4 + 1, v.y * ev);
        atomicAdd(sp + c * 4 + 2, v.z * ev);
        atomicAdd(sp + c * 4 + 3, v.w * ev);
      }
    }
  }
}

// A = normalize(lrelu(x @ w_self^T + (s/deg) @ w_neigh^T + bias)); in-place on A (holds s)
__global__ __launch_bounds__(256) void node_finalize(
    const float* __restrict__ x, const float* __restrict__ deg,
    const float* __restrict__ w_self, const float* __restrict__ w_neigh,
    const float* __restrict__ bias, float* __restrict__ A, int N)
{
  __shared__ float wsT[64][65];  // transposed + padded: conflict-free both ways
  __shared__ float wnT[64][65];
  const int tid = threadIdx.x, wave = tid >> 6, lane = tid & 63;
  for (int idx = tid; idx < 4096; idx += 256) {
    const int o = idx >> 6, i = idx & 63;
    wsT[i][o] = w_self[idx];
    wnT[i][o] = w_neigh[idx];
  }
  __syncthreads();
  for (long n = (long)blockIdx.x * 4 + wave; n < N; n += (long)gridDim.x * 4) {
    const float xv = x[n * 64 + lane];
    const float sv = A[n * 64 + lane];
    const float dg = deg[n];
    const float nb = sv / fmaxf(dg, 1.0f);
    float acc = bias[lane];
#pragma unroll
    for (int i = 0; i < 64; i++)
      acc += __shfl(xv, i) * wsT[i][lane] + __shfl(nb, i) * wnT[i][lane];
    const float al = lrelu(acc);
    float ss = al * al;
#pragma unroll
    for (int off = 1; off < 64; off <<= 1) ss += __shfl_xor(ss, off);
    const float nrm = fmaxf(sqrtf(ss), 1e-12f);
    A[n * 64 + lane] = al / nrm;
  }
}

__global__ void convert_w(const float* __restrict__ w1, const float* __restrict__ w2,
                          const float* __restrict__ w3,
                          u16* __restrict__ w1b, u16* __restrict__ w2b, u16* __restrict__ w3b)
{
  const int idx = blockIdx.x * 256 + threadIdx.x;
  if (idx < 16384) w1b[idx] = f2bf(w1[idx]);
  if (idx < 32768) w2b[idx] = f2bf(w2[idx]);
  if (idx < 8192)  w3b[idx] = f2bf(w3[idx]);
}

extern "C" void kernel_launch(void* const* d_in, const int* in_sizes, int n_in,
                              void* d_out, int out_size, void* d_ws, size_t ws_size,
                              hipStream_t stream)
{
  const float* x       = (const float*)d_in[0];
  const int*   src     = (const int*)d_in[1];
  const int*   dst     = (const int*)d_in[2];
  const float* w1      = (const float*)d_in[3];
  const float* b1      = (const float*)d_in[4];
  const float* w2      = (const float*)d_in[5];
  const float* b2      = (const float*)d_in[6];
  const float* w3      = (const float*)d_in[7];
  const float* b3      = (const float*)d_in[8];
  const float* w4      = (const float*)d_in[9];
  const float* b4      = (const float*)d_in[10];
  const float* w_self  = (const float*)d_in[11];
  const float* w_neigh = (const float*)d_in[12];
  const float* bias    = (const float*)d_in[13];

  const int N = in_sizes[0] / 64;
  const int E = in_sizes[1];

  float* A    = (float*)d_out;                    // [N,64]; also the s accumulator
  float* eout = (float*)d_out + (size_t)N * 64;   // [E]

  char* ws = (char*)d_ws;
  size_t off = ((size_t)N * 4 + 255) & ~(size_t)255;
  float* deg = (float*)ws;                         // N floats
  u16* w1b = (u16*)(ws + off); off += (size_t)16384 * 2;
  u16* w2b = (u16*)(ws + off); off += (size_t)32768 * 2;
  u16* w3b = (u16*)(ws + off);

  hipMemsetAsync(A, 0, (size_t)N * 64 * sizeof(float), stream);
  hipMemsetAsync(deg, 0, (size_t)N * sizeof(float), stream);

  convert_w<<<128, 256, 0, stream>>>(w1, w2, w3, w1b, w2b, w3b);

  const int nblk = (E + 63) / 64;
  edge_mlp<<<nblk, 256, 0, stream>>>(x, src, dst, w1b, w2b, w3b,
                                     b1, b2, b3, w4, b4, A, deg, eout, E);

  node_finalize<<<1024, 256, 0, stream>>>(x, deg, w_self, w_neigh, bias, A, N);
}

// Round 3
// 1810.304 us; speedup vs baseline: 1.7866x; 1.7866x over previous
//
#include <hip/hip_runtime.h>

typedef unsigned short u16;
typedef unsigned int   u32;
typedef __attribute__((ext_vector_type(8))) short short8;
typedef __attribute__((ext_vector_type(4))) float f32x4;

__device__ __forceinline__ u16 f2bf(float f) {
  u32 u = __float_as_uint(f);
  u += 0x7FFFu + ((u >> 16) & 1u);   // RNE
  return (u16)(u >> 16);
}
__device__ __forceinline__ u32 pk2(float lo, float hi) {
  return (u32)f2bf(lo) | ((u32)f2bf(hi) << 16);
}
__device__ __forceinline__ float lrelu(float v) { return v > 0.f ? v : 0.01f * v; }

// Channel permutation: physical output position c' = 32s+16a+4g+q holds logical
// channel sig(c') = 32s+8g+4a+q (swap a-bit and g-field). The packed bf16 MFMA
// output words, fed directly as next-layer B-fragments, land so that fragment
// slot kf receives physical channel sig^{-1}(kf) -> logical channel kf: the B
// operand is in LOGICAL k-order. Hence next-layer weights are permuted ONLY on
// the output (m) dimension.
__host__ __device__ __forceinline__ int sig(int c) {
  return ((c >> 5) << 5) | ((c & 12) << 1) | (((c >> 4) & 1) << 2) | (c & 3);
}

union U8 { u32 w[4]; short8 v; };

__global__ __launch_bounds__(256, 4) void edge_mlp(
    const float* __restrict__ x, const int* __restrict__ src, const int* __restrict__ dst,
    const u16* __restrict__ w1b, const u16* __restrict__ w2b, const u16* __restrict__ w3b,
    const float* __restrict__ b1p, const float* __restrict__ b2p, const float* __restrict__ b3p,
    const float* __restrict__ w4p, const float* __restrict__ b4,
    float* __restrict__ sacc, float* __restrict__ deg, float* __restrict__ eout, int E)
{
  const int lane = threadIdx.x & 63;
  const int wv   = threadIdx.x >> 6;
  const int g    = lane >> 4;      // k-group within wave
  const int r    = lane & 15;      // edge slot / weight row slot
  const int e    = (blockIdx.x * 4 + wv) * 16 + r;
  const int ec   = e < E ? e : E - 1;
  const int sn = src[ec], dn = dst[ec];

  // ---- gather: this lane's B-fragment slice of d = x[src]-x[dst] ----
  const float* xsr = x + (size_t)sn * 64 + 8 * g;
  const float* xdr = x + (size_t)dn * 64 + 8 * g;
  const float4 s0 = *(const float4*)(xsr);
  const float4 s1 = *(const float4*)(xsr + 4);
  const float4 s2 = *(const float4*)(xsr + 32);
  const float4 s3 = *(const float4*)(xsr + 36);
  const float4 d0 = *(const float4*)(xdr);
  const float4 d1 = *(const float4*)(xdr + 4);
  const float4 d2 = *(const float4*)(xdr + 32);
  const float4 d3 = *(const float4*)(xdr + 36);
  U8 bA, bB;
  bA.w[0] = pk2(s0.x - d0.x, s0.y - d0.y);
  bA.w[1] = pk2(s0.z - d0.z, s0.w - d0.w);
  bA.w[2] = pk2(s1.x - d1.x, s1.y - d1.y);
  bA.w[3] = pk2(s1.z - d1.z, s1.w - d1.w);
  bB.w[0] = pk2(s2.x - d2.x, s2.y - d2.y);
  bB.w[1] = pk2(s2.z - d2.z, s2.w - d2.w);
  bB.w[2] = pk2(s3.x - d3.x, s3.y - d3.y);
  bB.w[3] = pk2(s3.z - d3.z, s3.w - d3.w);

  // ---- layer 1: 256 <- 64 (16 tiles x 2 k-steps) ----
  f32x4 acc1[16] = {};
  const u16* w1l = w1b + (size_t)r * 64 + 8 * g;
#pragma unroll
  for (int t = 0; t < 16; t++) {
    short8 a0 = *(const short8*)(w1l + t * 1024);
    short8 a1 = *(const short8*)(w1l + t * 1024 + 32);
    acc1[t] = __builtin_amdgcn_mfma_f32_16x16x32_bf16(a0, bA.v, acc1[t], 0, 0, 0);
    acc1[t] = __builtin_amdgcn_mfma_f32_16x16x32_bf16(a1, bB.v, acc1[t], 0, 0, 0);
  }
  u32 h1p[32];
  {
    const float* b1l = b1p + 4 * g;
#pragma unroll
    for (int t = 0; t < 16; t++) {
      float4 bb = *(const float4*)(b1l + 16 * t);
      h1p[2 * t]     = pk2(lrelu(acc1[t][0] + bb.x), lrelu(acc1[t][1] + bb.y));
      h1p[2 * t + 1] = pk2(lrelu(acc1[t][2] + bb.z), lrelu(acc1[t][3] + bb.w));
    }
  }

  // ---- layer 2: 128 <- 256 (8 tiles x 8 k-steps); B-frags = h1p directly ----
  f32x4 acc2[8] = {};
  const u16* w2l = w2b + (size_t)r * 256 + 8 * g;
#pragma unroll
  for (int s = 0; s < 8; s++) {
    U8 bf;
    bf.w[0] = h1p[4 * s + 0]; bf.w[1] = h1p[4 * s + 1];
    bf.w[2] = h1p[4 * s + 2]; bf.w[3] = h1p[4 * s + 3];
#pragma unroll
    for (int t = 0; t < 8; t++) {
      short8 a = *(const short8*)(w2l + t * 4096 + 32 * s);
      acc2[t] = __builtin_amdgcn_mfma_f32_16x16x32_bf16(a, bf.v, acc2[t], 0, 0, 0);
    }
  }
  u32 h2p[16];
  {
    const float* b2l = b2p + 4 * g;
#pragma unroll
    for (int t = 0; t < 8; t++) {
      float4 bb = *(const float4*)(b2l + 16 * t);
      h2p[2 * t]     = pk2(lrelu(acc2[t][0] + bb.x), lrelu(acc2[t][1] + bb.y));
      h2p[2 * t + 1] = pk2(lrelu(acc2[t][2] + bb.z), lrelu(acc2[t][3] + bb.w));
    }
  }

  // ---- layer 3: 64 <- 128 (4 tiles x 4 k-steps) ----
  f32x4 acc3[4] = {};
  const u16* w3l = w3b + (size_t)r * 128 + 8 * g;
#pragma unroll
  for (int s = 0; s < 4; s++) {
    U8 bf;
    bf.w[0] = h2p[4 * s + 0]; bf.w[1] = h2p[4 * s + 1];
    bf.w[2] = h2p[4 * s + 2]; bf.w[3] = h2p[4 * s + 3];
#pragma unroll
    for (int t = 0; t < 4; t++) {
      short8 a = *(const short8*)(w3l + t * 2048 + 32 * s);
      acc3[t] = __builtin_amdgcn_mfma_f32_16x16x32_bf16(a, bf.v, acc3[t], 0, 0, 0);
    }
  }

  // ---- layer 4: dot(h3, w4) + sigmoid (per-lane partial, xor-reduce over g) ----
  float dot = 0.f;
  {
    const float* b3l = b3p + 4 * g;
    const float* w4l = w4p + 4 * g;
#pragma unroll
    for (int t = 0; t < 4; t++) {
      float4 bb = *(const float4*)(b3l + 16 * t);
      float4 ww = *(const float4*)(w4l + 16 * t);
      dot += lrelu(acc3[t][0] + bb.x) * ww.x + lrelu(acc3[t][1] + bb.y) * ww.y
           + lrelu(acc3[t][2] + bb.z) * ww.z + lrelu(acc3[t][3] + bb.w) * ww.w;
    }
  }
  dot += __shfl_xor(dot, 16);
  dot += __shfl_xor(dot, 32);
  const float ev = 1.f / (1.f + __expf(-(dot + b4[0])));

  // ---- outputs: e, deg, scatter msg = ev * x[src] into sacc ----
  if (e < E) {
    if (g == 0) {
      eout[e] = ev;
      atomicAdd(&deg[dn], 1.0f);
    }
    float* sp = sacc + (size_t)dn * 64 + 8 * g;
    atomicAdd(sp + 0, s0.x * ev);  atomicAdd(sp + 1, s0.y * ev);
    atomicAdd(sp + 2, s0.z * ev);  atomicAdd(sp + 3, s0.w * ev);
    atomicAdd(sp + 4, s1.x * ev);  atomicAdd(sp + 5, s1.y * ev);
    atomicAdd(sp + 6, s1.z * ev);  atomicAdd(sp + 7, s1.w * ev);
    atomicAdd(sp + 32, s2.x * ev); atomicAdd(sp + 33, s2.y * ev);
    atomicAdd(sp + 34, s2.z * ev); atomicAdd(sp + 35, s2.w * ev);
    atomicAdd(sp + 36, s3.x * ev); atomicAdd(sp + 37, s3.y * ev);
    atomicAdd(sp + 38, s3.z * ev); atomicAdd(sp + 39, s3.w * ev);
  }
}

// A = normalize(lrelu(x @ w_self^T + (s/deg) @ w_neigh^T + bias)); in-place on A (holds s)
__global__ __launch_bounds__(256) void node_finalize(
    const float* __restrict__ x, const float* __restrict__ deg,
    const float* __restrict__ w_self, const float* __restrict__ w_neigh,
    const float* __restrict__ bias, float* __restrict__ A, int N)
{
  __shared__ float wsT[64][65];
  __shared__ float wnT[64][65];
  const int tid = threadIdx.x, wave = tid >> 6, lane = tid & 63;
  for (int idx = tid; idx < 4096; idx += 256) {
    const int o = idx >> 6, i = idx & 63;
    wsT[i][o] = w_self[idx];
    wnT[i][o] = w_neigh[idx];
  }
  __syncthreads();
  for (long n = (long)blockIdx.x * 4 + wave; n < N; n += (long)gridDim.x * 4) {
    const float xv = x[n * 64 + lane];
    const float sv = A[n * 64 + lane];
    const float dg = deg[n];
    const float nb = sv / fmaxf(dg, 1.0f);
    float acc = bias[lane];
#pragma unroll
    for (int i = 0; i < 64; i++)
      acc += __shfl(xv, i) * wsT[i][lane] + __shfl(nb, i) * wnT[i][lane];
    const float al = lrelu(acc);
    float ss = al * al;
#pragma unroll
    for (int off = 1; off < 64; off <<= 1) ss += __shfl_xor(ss, off);
    const float nrm = fmaxf(sqrtf(ss), 1e-12f);
    A[n * 64 + lane] = al / nrm;
  }
}

// Convert weights to bf16. Output (m) dimension permuted by sig; k dimension
// stays LOGICAL (the repacked B-fragments arrive in logical k-order — see sig()
// comment). Biases/w4 gathered at physical positions.
__global__ void convert_w(const float* __restrict__ w1, const float* __restrict__ w2,
                          const float* __restrict__ w3,
                          const float* __restrict__ b1, const float* __restrict__ b2,
                          const float* __restrict__ b3, const float* __restrict__ w4,
                          u16* __restrict__ w1b, u16* __restrict__ w2b, u16* __restrict__ w3b,
                          float* __restrict__ b1p, float* __restrict__ b2p,
                          float* __restrict__ b3p, float* __restrict__ w4p)
{
  const int idx = blockIdx.x * 256 + threadIdx.x;
  if (idx < 16384) { int c = idx >> 6, k = idx & 63;  w1b[idx] = f2bf(w1[sig(c) * 64 + k]); }
  if (idx < 32768) { int m = idx >> 8, k = idx & 255; w2b[idx] = f2bf(w2[sig(m) * 256 + k]); }
  if (idx < 8192)  { int m = idx >> 7, k = idx & 127; w3b[idx] = f2bf(w3[sig(m) * 128 + k]); }
  if (idx < 256) b1p[idx] = b1[sig(idx)];
  if (idx < 128) b2p[idx] = b2[sig(idx)];
  if (idx < 64)  { b3p[idx] = b3[sig(idx)]; w4p[idx] = w4[sig(idx)]; }
}

extern "C" void kernel_launch(void* const* d_in, const int* in_sizes, int n_in,
                              void* d_out, int out_size, void* d_ws, size_t ws_size,
                              hipStream_t stream)
{
  const float* x       = (const float*)d_in[0];
  const int*   src     = (const int*)d_in[1];
  const int*   dst     = (const int*)d_in[2];
  const float* w1      = (const float*)d_in[3];
  const float* b1      = (const float*)d_in[4];
  const float* w2      = (const float*)d_in[5];
  const float* b2      = (const float*)d_in[6];
  const float* w3      = (const float*)d_in[7];
  const float* b3      = (const float*)d_in[8];
  const float* w4      = (const float*)d_in[9];
  const float* b4      = (const float*)d_in[10];
  const float* w_self  = (const float*)d_in[11];
  const float* w_neigh = (const float*)d_in[12];
  const float* bias    = (const float*)d_in[13];

  const int N = in_sizes[0] / 64;
  const int E = in_sizes[1];

  float* A    = (float*)d_out;                    // [N,64]; also the s accumulator
  float* eout = (float*)d_out + (size_t)N * 64;   // [E]

  char* ws = (char*)d_ws;
  size_t off = ((size_t)N * 4 + 255) & ~(size_t)255;
  float* deg = (float*)ws;
  u16* w1b = (u16*)(ws + off); off += (size_t)16384 * 2;
  u16* w2b = (u16*)(ws + off); off += (size_t)32768 * 2;
  u16* w3b = (u16*)(ws + off); off += (size_t)8192 * 2;
  off = (off + 255) & ~(size_t)255;
  float* b1p = (float*)(ws + off); off += 256 * 4;
  float* b2p = (float*)(ws + off); off += 128 * 4;
  float* b3p = (float*)(ws + off); off += 64 * 4;
  float* w4p = (float*)(ws + off);

  hipMemsetAsync(A, 0, (size_t)N * 64 * sizeof(float), stream);
  hipMemsetAsync(deg, 0, (size_t)N * sizeof(float), stream);

  convert_w<<<128, 256, 0, stream>>>(w1, w2, w3, b1, b2, b3, w4,
                                     w1b, w2b, w3b, b1p, b2p, b3p, w4p);

  const int nblk = (E + 63) / 64;
  edge_mlp<<<nblk, 256, 0, stream>>>(x, src, dst, w1b, w2b, w3b,
                                     b1p, b2p, b3p, w4p, b4, A, deg, eout, E);

  node_finalize<<<1024, 256, 0, stream>>>(x, deg, w_self, w_neigh, bias, A, N);
}

// Round 4
// 1038.391 us; speedup vs baseline: 3.1148x; 1.7434x over previous
//
#include <hip/hip_runtime.h>

typedef unsigned short u16;
typedef unsigned int   u32;
typedef __attribute__((ext_vector_type(8))) short short8;
typedef __attribute__((ext_vector_type(4))) float f32x4;

__device__ __forceinline__ u16 f2bf(float f) {
  u32 u = __float_as_uint(f);
  u += 0x7FFFu + ((u >> 16) & 1u);   // RNE
  return (u16)(u >> 16);
}
__device__ __forceinline__ u32 pk2(float lo, float hi) {
  return (u32)f2bf(lo) | ((u32)f2bf(hi) << 16);
}
__device__ __forceinline__ float lrelu(float v) { return v > 0.f ? v : 0.01f * v; }

// Channel permutation: physical output position c' = 32s+16a+4g+q holds logical
// channel sig(c') = 32s+8g+4a+q. Packed bf16 MFMA outputs fed directly as
// next-layer B-fragments arrive in LOGICAL k-order -> next-layer weights are
// permuted only on the output (m) dimension. (Verified round 3.)
__host__ __device__ __forceinline__ int sig(int c) {
  return ((c >> 5) << 5) | ((c & 12) << 1) | (((c >> 4) & 1) << 2) | (c & 3);
}

union U8 { u32 w[4]; short8 v; };

// ---------------- edge MLP: e = sigmoid(MLP(x[src]-x[dst])), deg histogram ----
__global__ __launch_bounds__(256, 4) void edge_mlp(
    const float* __restrict__ x, const int* __restrict__ src, const int* __restrict__ dst,
    const u16* __restrict__ w1b, const u16* __restrict__ w2b, const u16* __restrict__ w3b,
    const float* __restrict__ b1p, const float* __restrict__ b2p, const float* __restrict__ b3p,
    const float* __restrict__ w4p, const float* __restrict__ b4,
    int* __restrict__ degi, float* __restrict__ eout, int E)
{
  const int lane = threadIdx.x & 63;
  const int wv   = threadIdx.x >> 6;
  const int g    = lane >> 4;      // k-group within wave
  const int r    = lane & 15;      // edge slot / weight row slot
  const int e    = (blockIdx.x * 4 + wv) * 16 + r;
  const int ec   = e < E ? e : E - 1;
  const int sn = src[ec], dn = dst[ec];

  // ---- gather: this lane's B-fragment slice of d = x[src]-x[dst] ----
  const float* xsr = x + (size_t)sn * 64 + 8 * g;
  const float* xdr = x + (size_t)dn * 64 + 8 * g;
  const float4 s0 = *(const float4*)(xsr);
  const float4 s1 = *(const float4*)(xsr + 4);
  const float4 s2 = *(const float4*)(xsr + 32);
  const float4 s3 = *(const float4*)(xsr + 36);
  const float4 d0 = *(const float4*)(xdr);
  const float4 d1 = *(const float4*)(xdr + 4);
  const float4 d2 = *(const float4*)(xdr + 32);
  const float4 d3 = *(const float4*)(xdr + 36);
  U8 bA, bB;
  bA.w[0] = pk2(s0.x - d0.x, s0.y - d0.y);
  bA.w[1] = pk2(s0.z - d0.z, s0.w - d0.w);
  bA.w[2] = pk2(s1.x - d1.x, s1.y - d1.y);
  bA.w[3] = pk2(s1.z - d1.z, s1.w - d1.w);
  bB.w[0] = pk2(s2.x - d2.x, s2.y - d2.y);
  bB.w[1] = pk2(s2.z - d2.z, s2.w - d2.w);
  bB.w[2] = pk2(s3.x - d3.x, s3.y - d3.y);
  bB.w[3] = pk2(s3.z - d3.z, s3.w - d3.w);

  // ---- layer 1: 256 <- 64 ----
  f32x4 acc1[16] = {};
  const u16* w1l = w1b + (size_t)r * 64 + 8 * g;
#pragma unroll
  for (int t = 0; t < 16; t++) {
    short8 a0 = *(const short8*)(w1l + t * 1024);
    short8 a1 = *(const short8*)(w1l + t * 1024 + 32);
    acc1[t] = __builtin_amdgcn_mfma_f32_16x16x32_bf16(a0, bA.v, acc1[t], 0, 0, 0);
    acc1[t] = __builtin_amdgcn_mfma_f32_16x16x32_bf16(a1, bB.v, acc1[t], 0, 0, 0);
  }
  u32 h1p[32];
  {
    const float* b1l = b1p + 4 * g;
#pragma unroll
    for (int t = 0; t < 16; t++) {
      float4 bb = *(const float4*)(b1l + 16 * t);
      h1p[2 * t]     = pk2(lrelu(acc1[t][0] + bb.x), lrelu(acc1[t][1] + bb.y));
      h1p[2 * t + 1] = pk2(lrelu(acc1[t][2] + bb.z), lrelu(acc1[t][3] + bb.w));
    }
  }

  // ---- layer 2: 128 <- 256 ----
  f32x4 acc2[8] = {};
  const u16* w2l = w2b + (size_t)r * 256 + 8 * g;
#pragma unroll
  for (int s = 0; s < 8; s++) {
    U8 bf;
    bf.w[0] = h1p[4 * s + 0]; bf.w[1] = h1p[4 * s + 1];
    bf.w[2] = h1p[4 * s + 2]; bf.w[3] = h1p[4 * s + 3];
#pragma unroll
    for (int t = 0; t < 8; t++) {
      short8 a = *(const short8*)(w2l + t * 4096 + 32 * s);
      acc2[t] = __builtin_amdgcn_mfma_f32_16x16x32_bf16(a, bf.v, acc2[t], 0, 0, 0);
    }
  }
  u32 h2p[16];
  {
    const float* b2l = b2p + 4 * g;
#pragma unroll
    for (int t = 0; t < 8; t++) {
      float4 bb = *(const float4*)(b2l + 16 * t);
      h2p[2 * t]     = pk2(lrelu(acc2[t][0] + bb.x), lrelu(acc2[t][1] + bb.y));
      h2p[2 * t + 1] = pk2(lrelu(acc2[t][2] + bb.z), lrelu(acc2[t][3] + bb.w));
    }
  }

  // ---- layer 3: 64 <- 128 ----
  f32x4 acc3[4] = {};
  const u16* w3l = w3b + (size_t)r * 128 + 8 * g;
#pragma unroll
  for (int s = 0; s < 4; s++) {
    U8 bf;
    bf.w[0] = h2p[4 * s + 0]; bf.w[1] = h2p[4 * s + 1];
    bf.w[2] = h2p[4 * s + 2]; bf.w[3] = h2p[4 * s + 3];
#pragma unroll
    for (int t = 0; t < 4; t++) {
      short8 a = *(const short8*)(w3l + t * 2048 + 32 * s);
      acc3[t] = __builtin_amdgcn_mfma_f32_16x16x32_bf16(a, bf.v, acc3[t], 0, 0, 0);
    }
  }

  // ---- layer 4: dot + sigmoid ----
  float dot = 0.f;
  {
    const float* b3l = b3p + 4 * g;
    const float* w4l = w4p + 4 * g;
#pragma unroll
    for (int t = 0; t < 4; t++) {
      float4 bb = *(const float4*)(b3l + 16 * t);
      float4 ww = *(const float4*)(w4l + 16 * t);
      dot += lrelu(acc3[t][0] + bb.x) * ww.x + lrelu(acc3[t][1] + bb.y) * ww.y
           + lrelu(acc3[t][2] + bb.z) * ww.z + lrelu(acc3[t][3] + bb.w) * ww.w;
    }
  }
  dot += __shfl_xor(dot, 16);
  dot += __shfl_xor(dot, 32);
  const float ev = 1.f / (1.f + __expf(-(dot + b4[0])));

  if (e < E && g == 0) {
    eout[e] = ev;
    atomicAdd(&degi[dn], 1);
  }
}

// ---------------- CSR build: exclusive scan of degi ----------------
__global__ void scan_part(const int* __restrict__ degi, int* __restrict__ rowptr,
                          int* __restrict__ bsum, int N)
{
  __shared__ int wsum[4];
  const int tid = threadIdx.x, lane = tid & 63, w = tid >> 6;
  const int base = blockIdx.x * 1024 + tid * 4;
  int d0 = 0, d1 = 0, d2 = 0, d3 = 0;
  if (base + 3 < N) {
    int4 v = *(const int4*)(degi + base);
    d0 = v.x; d1 = v.y; d2 = v.z; d3 = v.w;
  } else {
    if (base < N)     d0 = degi[base];
    if (base + 1 < N) d1 = degi[base + 1];
    if (base + 2 < N) d2 = degi[base + 2];
    if (base + 3 < N) d3 = degi[base + 3];
  }
  const int ts = d0 + d1 + d2 + d3;
  int sc = ts;
#pragma unroll
  for (int o = 1; o < 64; o <<= 1) { int v = __shfl_up(sc, o); if (lane >= o) sc += v; }
  if (lane == 63) wsum[w] = sc;
  __syncthreads();
  int woff = 0;
  for (int i = 0; i < w; i++) woff += wsum[i];
  const int ex = woff + sc - ts;
  if (base < N)     rowptr[base]     = ex;
  if (base + 1 < N) rowptr[base + 1] = ex + d0;
  if (base + 2 < N) rowptr[base + 2] = ex + d0 + d1;
  if (base + 3 < N) rowptr[base + 3] = ex + d0 + d1 + d2;
  if (tid == 255) bsum[blockIdx.x] = woff + sc;
}

__global__ void scan_bsum(int* __restrict__ bsum, int nb)  // nb <= 256
{
  __shared__ int wsum[4];
  const int tid = threadIdx.x, lane = tid & 63, w = tid >> 6;
  const int v = tid < nb ? bsum[tid] : 0;
  int sc = v;
#pragma unroll
  for (int o = 1; o < 64; o <<= 1) { int t = __shfl_up(sc, o); if (lane >= o) sc += t; }
  if (lane == 63) wsum[w] = sc;
  __syncthreads();
  int woff = 0;
  for (int i = 0; i < w; i++) woff += wsum[i];
  if (tid < nb) bsum[tid] = woff + sc - v;
}

__global__ void scan_add(int* __restrict__ rowptr, const int* __restrict__ bsum,
                         int* __restrict__ cursor, int N, int E)
{
  const int base = blockIdx.x * 1024 + threadIdx.x * 4;
  const int off = bsum[blockIdx.x];
#pragma unroll
  for (int i = 0; i < 4; i++)
    if (base + i < N) { rowptr[base + i] += off; cursor[base + i] = 0; }
  if (blockIdx.x == 0 && threadIdx.x == 0) rowptr[N] = E;
}

// ---------------- bin edges: ebin2[pos] = {src, bits(e)} ----------------
__global__ void scatter_bin(const int* __restrict__ src, const int* __restrict__ dst,
                            const float* __restrict__ eout, const int* __restrict__ rowptr,
                            int* __restrict__ cursor, int2* __restrict__ ebin2, int E)
{
  const int eid = blockIdx.x * 256 + threadIdx.x;
  if (eid >= E) return;
  const int dn = dst[eid];
  const int pos = rowptr[dn] + atomicAdd(&cursor[dn], 1);
  int2 v;
  v.x = src[eid];
  v.y = __float_as_int(eout[eid]);
  ebin2[pos] = v;
}

// ---------------- per-node aggregate + SAGE finalize (fused) ----------------
__global__ __launch_bounds__(256, 4) void node_agg(
    const float* __restrict__ x, const int* __restrict__ rowptr,
    const int2* __restrict__ ebin2, const float* __restrict__ w_self,
    const float* __restrict__ w_neigh, const float* __restrict__ bias,
    float* __restrict__ A, int N)
{
  __shared__ float wsT[64][65];
  __shared__ float wnT[64][65];
  const int tid = threadIdx.x, w = tid >> 6, lane = tid & 63;
  for (int idx = tid; idx < 4096; idx += 256) {
    const int o = idx >> 6, i = idx & 63;
    wsT[i][o] = w_self[idx];
    wnT[i][o] = w_neigh[idx];
  }
  __syncthreads();
  for (int n = blockIdx.x * 4 + w; n < N; n += gridDim.x * 4) {
    const int s = rowptr[n], t = rowptr[n + 1];
    float acc = 0.f;
    int j = s;
    for (; j + 4 <= t; j += 4) {
      const int2 p0 = ebin2[j], p1 = ebin2[j + 1], p2 = ebin2[j + 2], p3 = ebin2[j + 3];
      acc += __int_as_float(p0.y) * x[(size_t)p0.x * 64 + lane]
           + __int_as_float(p1.y) * x[(size_t)p1.x * 64 + lane]
           + __int_as_float(p2.y) * x[(size_t)p2.x * 64 + lane]
           + __int_as_float(p3.y) * x[(size_t)p3.x * 64 + lane];
    }
    for (; j < t; j++) {
      const int2 p = ebin2[j];
      acc += __int_as_float(p.y) * x[(size_t)p.x * 64 + lane];
    }
    const float dg = (float)(t - s);
    const float nb = acc / fmaxf(dg, 1.0f);
    const float xv = x[(size_t)n * 64 + lane];
    float a = bias[lane];
#pragma unroll
    for (int i = 0; i < 64; i++)
      a += __shfl(xv, i) * wsT[i][lane] + __shfl(nb, i) * wnT[i][lane];
    a = lrelu(a);
    float ss = a * a;
#pragma unroll
    for (int off = 1; off < 64; off <<= 1) ss += __shfl_xor(ss, off);
    A[(size_t)n * 64 + lane] = a / fmaxf(sqrtf(ss), 1e-12f);
  }
}

// ---------------- weight conversion (round-3 verified permutation) ----------
__global__ void convert_w(const float* __restrict__ w1, const float* __restrict__ w2,
                          const float* __restrict__ w3,
                          const float* __restrict__ b1, const float* __restrict__ b2,
                          const float* __restrict__ b3, const float* __restrict__ w4,
                          u16* __restrict__ w1b, u16* __restrict__ w2b, u16* __restrict__ w3b,
                          float* __restrict__ b1p, float* __restrict__ b2p,
                          float* __restrict__ b3p, float* __restrict__ w4p)
{
  const int idx = blockIdx.x * 256 + threadIdx.x;
  if (idx < 16384) { int c = idx >> 6, k = idx & 63;  w1b[idx] = f2bf(w1[sig(c) * 64 + k]); }
  if (idx < 32768) { int m = idx >> 8, k = idx & 255; w2b[idx] = f2bf(w2[sig(m) * 256 + k]); }
  if (idx < 8192)  { int m = idx >> 7, k = idx & 127; w3b[idx] = f2bf(w3[sig(m) * 128 + k]); }
  if (idx < 256) b1p[idx] = b1[sig(idx)];
  if (idx < 128) b2p[idx] = b2[sig(idx)];
  if (idx < 64)  { b3p[idx] = b3[sig(idx)]; w4p[idx] = w4[sig(idx)]; }
}

extern "C" void kernel_launch(void* const* d_in, const int* in_sizes, int n_in,
                              void* d_out, int out_size, void* d_ws, size_t ws_size,
                              hipStream_t stream)
{
  const float* x       = (const float*)d_in[0];
  const int*   src     = (const int*)d_in[1];
  const int*   dst     = (const int*)d_in[2];
  const float* w1      = (const float*)d_in[3];
  const float* b1      = (const float*)d_in[4];
  const float* w2      = (const float*)d_in[5];
  const float* b2      = (const float*)d_in[6];
  const float* w3      = (const float*)d_in[7];
  const float* b3      = (const float*)d_in[8];
  const float* w4      = (const float*)d_in[9];
  const float* b4      = (const float*)d_in[10];
  const float* w_self  = (const float*)d_in[11];
  const float* w_neigh = (const float*)d_in[12];
  const float* bias    = (const float*)d_in[13];

  const int N = in_sizes[0] / 64;
  const int E = in_sizes[1];

  float* A    = (float*)d_out;                    // [N,64]
  float* eout = (float*)d_out + (size_t)N * 64;   // [E]

  char* ws = (char*)d_ws;
  size_t off = 0;
  auto alloc = [&](size_t bytes) {
    void* p = ws + off;
    off = (off + bytes + 255) & ~(size_t)255;
    return p;
  };
  int*  degi   = (int*)alloc((size_t)N * 4);
  int*  rowptr = (int*)alloc((size_t)(N + 1) * 4);
  int*  cursor = (int*)alloc((size_t)N * 4);
  int*  bsum   = (int*)alloc(1024 * 4);
  int2* ebin2  = (int2*)alloc((size_t)E * 8);
  u16* w1b = (u16*)alloc((size_t)16384 * 2);
  u16* w2b = (u16*)alloc((size_t)32768 * 2);
  u16* w3b = (u16*)alloc((size_t)8192 * 2);
  float* b1p = (float*)alloc(256 * 4);
  float* b2p = (float*)alloc(128 * 4);
  float* b3p = (float*)alloc(64 * 4);
  float* w4p = (float*)alloc(64 * 4);

  hipMemsetAsync(degi, 0, (size_t)N * sizeof(int), stream);

  convert_w<<<128, 256, 0, stream>>>(w1, w2, w3, b1, b2, b3, w4,
                                     w1b, w2b, w3b, b1p, b2p, b3p, w4p);

  const int nblk = (E + 63) / 64;
  edge_mlp<<<nblk, 256, 0, stream>>>(x, src, dst, w1b, w2b, w3b,
                                     b1p, b2p, b3p, w4p, b4, degi, eout, E);

  const int nsb = (N + 1023) / 1024;   // scan blocks (<= 256 for N <= 262144)
  scan_part<<<nsb, 256, 0, stream>>>(degi, rowptr, bsum, N);
  scan_bsum<<<1, 256, 0, stream>>>(bsum, nsb);
  scan_add<<<nsb, 256, 0, stream>>>(rowptr, bsum, cursor, N, E);

  scatter_bin<<<(E + 255) / 256, 256, 0, stream>>>(src, dst, eout, rowptr, cursor, ebin2, E);

  node_agg<<<2048, 256, 0, stream>>>(x, rowptr, ebin2, w_self, w_neigh, bias, A, N);
}

// Round 5
// 579.406 us; speedup vs baseline: 5.5822x; 1.7922x over previous
//
#include <hip/hip_runtime.h>

typedef unsigned short u16;
typedef unsigned int   u32;
typedef __attribute__((ext_vector_type(8))) short short8;
typedef __attribute__((ext_vector_type(4))) float f32x4;

__device__ __forceinline__ u16 f2bf(float f) {
  u32 u = __float_as_uint(f);
  u += 0x7FFFu + ((u >> 16) & 1u);   // RNE
  return (u16)(u >> 16);
}
__device__ __forceinline__ u32 pk2(float lo, float hi) {
  return (u32)f2bf(lo) | ((u32)f2bf(hi) << 16);
}
__device__ __forceinline__ float lrelu(float v) { return v > 0.f ? v : 0.01f * v; }

// Channel permutation (verified round 3): physical output position c'=32s+16a+4g+q
// holds logical channel sig(c'). Packed bf16 MFMA outputs fed directly as
// next-layer B-fragments arrive in LOGICAL k-order -> next-layer weights
// permuted only on the output (m) dimension.
__host__ __device__ __forceinline__ int sig(int c) {
  return ((c >> 5) << 5) | ((c & 12) << 1) | (((c >> 4) & 1) << 2) | (c & 3);
}

union U8 { u32 w[4]; short8 v; };

#define MFMA16(A, B, C) __builtin_amdgcn_mfma_f32_16x16x32_bf16(A, B, C, 0, 0, 0)

// LDS chunk bases in short8 units: w1 [0,2048), w2 [2048,6144), w3 [6144,7168)
#define W2_BASE 2048
#define W3_BASE 6144
#define NCHUNK8 7168   // 114688 bytes total

// ---------------- edge MLP: LDS-staged weights, 32 edges/wave, fused scatter --
__global__ __launch_bounds__(512, 2) void edge_mlp(
    const float* __restrict__ x, const int* __restrict__ src, const int* __restrict__ dst,
    const short8* __restrict__ wcat,
    const float* __restrict__ b1p, const float* __restrict__ b2p, const float* __restrict__ b3p,
    const float* __restrict__ w4p, const float* __restrict__ b4,
    const int* __restrict__ rowptr, int* __restrict__ cursor, int2* __restrict__ ebin2,
    float* __restrict__ eout, int E)
{
  __shared__ short8 ldsw[NCHUNK8];   // 112 KiB -> 1 block/CU (intentional)
  const int tid = threadIdx.x;
  for (int i = tid; i < NCHUNK8; i += 512) ldsw[i] = wcat[i];   // 14 iters/thread
  __syncthreads();

  const int lane = tid & 63;
  const int wv   = tid >> 6;
  const int g    = lane >> 4;      // k-group
  const int r    = lane & 15;      // edge slot / weight row slot
  const int eb   = (blockIdx.x * 8 + wv) * 32;
  const int e0   = eb + r, e1 = eb + 16 + r;
  const int ec0  = e0 < E ? e0 : E - 1;
  const int ec1  = e1 < E ? e1 : E - 1;
  const int sn0 = src[ec0], dn0 = dst[ec0];
  const int sn1 = src[ec1], dn1 = dst[ec1];
  const float b4v = b4[0];

  // ---- gather both edge-sets' B-fragment slices of d = x[src]-x[dst] ----
  U8 bA0, bB0, bA1, bB1;
  {
    const float* xsr = x + (size_t)sn0 * 64 + 8 * g;
    const float* xdr = x + (size_t)dn0 * 64 + 8 * g;
    float4 s0 = *(const float4*)(xsr),      s1 = *(const float4*)(xsr + 4);
    float4 s2 = *(const float4*)(xsr + 32), s3 = *(const float4*)(xsr + 36);
    float4 d0 = *(const float4*)(xdr),      d1 = *(const float4*)(xdr + 4);
    float4 d2 = *(const float4*)(xdr + 32), d3 = *(const float4*)(xdr + 36);
    bA0.w[0] = pk2(s0.x - d0.x, s0.y - d0.y); bA0.w[1] = pk2(s0.z - d0.z, s0.w - d0.w);
    bA0.w[2] = pk2(s1.x - d1.x, s1.y - d1.y); bA0.w[3] = pk2(s1.z - d1.z, s1.w - d1.w);
    bB0.w[0] = pk2(s2.x - d2.x, s2.y - d2.y); bB0.w[1] = pk2(s2.z - d2.z, s2.w - d2.w);
    bB0.w[2] = pk2(s3.x - d3.x, s3.y - d3.y); bB0.w[3] = pk2(s3.z - d3.z, s3.w - d3.w);
  }
  {
    const float* xsr = x + (size_t)sn1 * 64 + 8 * g;
    const float* xdr = x + (size_t)dn1 * 64 + 8 * g;
    float4 s0 = *(const float4*)(xsr),      s1 = *(const float4*)(xsr + 4);
    float4 s2 = *(const float4*)(xsr + 32), s3 = *(const float4*)(xsr + 36);
    float4 d0 = *(const float4*)(xdr),      d1 = *(const float4*)(xdr + 4);
    float4 d2 = *(const float4*)(xdr + 32), d3 = *(const float4*)(xdr + 36);
    bA1.w[0] = pk2(s0.x - d0.x, s0.y - d0.y); bA1.w[1] = pk2(s0.z - d0.z, s0.w - d0.w);
    bA1.w[2] = pk2(s1.x - d1.x, s1.y - d1.y); bA1.w[3] = pk2(s1.z - d1.z, s1.w - d1.w);
    bB1.w[0] = pk2(s2.x - d2.x, s2.y - d2.y); bB1.w[1] = pk2(s2.z - d2.z, s2.w - d2.w);
    bB1.w[2] = pk2(s3.x - d3.x, s3.y - d3.y); bB1.w[3] = pk2(s3.z - d3.z, s3.w - d3.w);
  }

  // ---- layer 1: 256 <- 64 (tile-local acc, both sets) ----
  u32 h1a[32], h1b[32];
  {
    const float* b1l = b1p + 4 * g;
#pragma unroll
    for (int t = 0; t < 16; t++) {
      short8 a0 = ldsw[(t * 2 + 0) * 64 + lane];
      short8 a1 = ldsw[(t * 2 + 1) * 64 + lane];
      f32x4 p = {}, q = {};
      p = MFMA16(a0, bA0.v, p); p = MFMA16(a1, bB0.v, p);
      q = MFMA16(a0, bA1.v, q); q = MFMA16(a1, bB1.v, q);
      float4 bb = *(const float4*)(b1l + 16 * t);
      h1a[2 * t]     = pk2(lrelu(p[0] + bb.x), lrelu(p[1] + bb.y));
      h1a[2 * t + 1] = pk2(lrelu(p[2] + bb.z), lrelu(p[3] + bb.w));
      h1b[2 * t]     = pk2(lrelu(q[0] + bb.x), lrelu(q[1] + bb.y));
      h1b[2 * t + 1] = pk2(lrelu(q[2] + bb.z), lrelu(q[3] + bb.w));
    }
  }

  // ---- layer 2: 128 <- 256 ----
  u32 h2a[16], h2b[16];
  {
    const float* b2l = b2p + 4 * g;
#pragma unroll
    for (int t = 0; t < 8; t++) {
      f32x4 p = {}, q = {};
#pragma unroll
      for (int s = 0; s < 8; s++) {
        short8 a = ldsw[W2_BASE + (t * 8 + s) * 64 + lane];
        U8 f0, f1;
        f0.w[0] = h1a[4 * s + 0]; f0.w[1] = h1a[4 * s + 1];
        f0.w[2] = h1a[4 * s + 2]; f0.w[3] = h1a[4 * s + 3];
        f1.w[0] = h1b[4 * s + 0]; f1.w[1] = h1b[4 * s + 1];
        f1.w[2] = h1b[4 * s + 2]; f1.w[3] = h1b[4 * s + 3];
        p = MFMA16(a, f0.v, p);
        q = MFMA16(a, f1.v, q);
      }
      float4 bb = *(const float4*)(b2l + 16 * t);
      h2a[2 * t]     = pk2(lrelu(p[0] + bb.x), lrelu(p[1] + bb.y));
      h2a[2 * t + 1] = pk2(lrelu(p[2] + bb.z), lrelu(p[3] + bb.w));
      h2b[2 * t]     = pk2(lrelu(q[0] + bb.x), lrelu(q[1] + bb.y));
      h2b[2 * t + 1] = pk2(lrelu(q[2] + bb.z), lrelu(q[3] + bb.w));
    }
  }

  // ---- layer 3 + layer 4 fused: dot accumulates per tile ----
  float dot0 = 0.f, dot1 = 0.f;
  {
    const float* b3l = b3p + 4 * g;
    const float* w4l = w4p + 4 * g;
#pragma unroll
    for (int t = 0; t < 4; t++) {
      f32x4 p = {}, q = {};
#pragma unroll
      for (int s = 0; s < 4; s++) {
        short8 a = ldsw[W3_BASE + (t * 4 + s) * 64 + lane];
        U8 f0, f1;
        f0.w[0] = h2a[4 * s + 0]; f0.w[1] = h2a[4 * s + 1];
        f0.w[2] = h2a[4 * s + 2]; f0.w[3] = h2a[4 * s + 3];
        f1.w[0] = h2b[4 * s + 0]; f1.w[1] = h2b[4 * s + 1];
        f1.w[2] = h2b[4 * s + 2]; f1.w[3] = h2b[4 * s + 3];
        p = MFMA16(a, f0.v, p);
        q = MFMA16(a, f1.v, q);
      }
      float4 bb = *(const float4*)(b3l + 16 * t);
      float4 ww = *(const float4*)(w4l + 16 * t);
      dot0 += lrelu(p[0] + bb.x) * ww.x + lrelu(p[1] + bb.y) * ww.y
            + lrelu(p[2] + bb.z) * ww.z + lrelu(p[3] + bb.w) * ww.w;
      dot1 += lrelu(q[0] + bb.x) * ww.x + lrelu(q[1] + bb.y) * ww.y
            + lrelu(q[2] + bb.z) * ww.z + lrelu(q[3] + bb.w) * ww.w;
    }
  }
  dot0 += __shfl_xor(dot0, 16); dot0 += __shfl_xor(dot0, 32);
  dot1 += __shfl_xor(dot1, 16); dot1 += __shfl_xor(dot1, 32);
  const float ev0 = 1.f / (1.f + __expf(-(dot0 + b4v)));
  const float ev1 = 1.f / (1.f + __expf(-(dot1 + b4v)));

  // ---- outputs: eout + direct CSR scatter {src, e} ----
  if (g == 0) {
    if (e0 < E) {
      eout[e0] = ev0;
      const int pos = rowptr[dn0] + atomicAdd(&cursor[dn0], 1);
      int2 v; v.x = sn0; v.y = __float_as_int(ev0);
      ebin2[pos] = v;
    }
    if (e1 < E) {
      eout[e1] = ev1;
      const int pos = rowptr[dn1] + atomicAdd(&cursor[dn1], 1);
      int2 v; v.x = sn1; v.y = __float_as_int(ev1);
      ebin2[pos] = v;
    }
  }
}

// ---------------- degree histogram ----------------
__global__ void deg_hist(const int* __restrict__ dst, int* __restrict__ degi, int E)
{
  const int i = blockIdx.x * 256 + threadIdx.x;
  if (i < E) atomicAdd(&degi[dst[i]], 1);
}

// ---------------- CSR build: exclusive scan of degi ----------------
__global__ void scan_part(const int* __restrict__ degi, int* __restrict__ rowptr,
                          int* __restrict__ bsum, int N)
{
  __shared__ int wsum[4];
  const int tid = threadIdx.x, lane = tid & 63, w = tid >> 6;
  const int base = blockIdx.x * 1024 + tid * 4;
  int d0 = 0, d1 = 0, d2 = 0, d3 = 0;
  if (base + 3 < N) {
    int4 v = *(const int4*)(degi + base);
    d0 = v.x; d1 = v.y; d2 = v.z; d3 = v.w;
  } else {
    if (base < N)     d0 = degi[base];
    if (base + 1 < N) d1 = degi[base + 1];
    if (base + 2 < N) d2 = degi[base + 2];
    if (base + 3 < N) d3 = degi[base + 3];
  }
  const int ts = d0 + d1 + d2 + d3;
  int sc = ts;
#pragma unroll
  for (int o = 1; o < 64; o <<= 1) { int v = __shfl_up(sc, o); if (lane >= o) sc += v; }
  if (lane == 63) wsum[w] = sc;
  __syncthreads();
  int woff = 0;
  for (int i = 0; i < w; i++) woff += wsum[i];
  const int ex = woff + sc - ts;
  if (base < N)     rowptr[base]     = ex;
  if (base + 1 < N) rowptr[base + 1] = ex + d0;
  if (base + 2 < N) rowptr[base + 2] = ex + d0 + d1;
  if (base + 3 < N) rowptr[base + 3] = ex + d0 + d1 + d2;
  if (tid == 255) bsum[blockIdx.x] = woff + sc;
}

__global__ void scan_bsum(int* __restrict__ bsum, int nb)  // nb <= 256
{
  __shared__ int wsum[4];
  const int tid = threadIdx.x, lane = tid & 63, w = tid >> 6;
  const int v = tid < nb ? bsum[tid] : 0;
  int sc = v;
#pragma unroll
  for (int o = 1; o < 64; o <<= 1) { int t = __shfl_up(sc, o); if (lane >= o) sc += t; }
  if (lane == 63) wsum[w] = sc;
  __syncthreads();
  int woff = 0;
  for (int i = 0; i < w; i++) woff += wsum[i];
  if (tid < nb) bsum[tid] = woff + sc - v;
}

__global__ void scan_add(int* __restrict__ rowptr, const int* __restrict__ bsum,
                         int* __restrict__ cursor, int N, int E)
{
  const int base = blockIdx.x * 1024 + threadIdx.x * 4;
  const int off = bsum[blockIdx.x];
#pragma unroll
  for (int i = 0; i < 4; i++)
    if (base + i < N) { rowptr[base + i] += off; cursor[base + i] = 0; }
  if (blockIdx.x == 0 && threadIdx.x == 0) rowptr[N] = E;
}

// ---------------- per-node aggregate + SAGE finalize (fused) ----------------
__global__ __launch_bounds__(256, 4) void node_agg(
    const float* __restrict__ x, const int* __restrict__ rowptr,
    const int2* __restrict__ ebin2, const float* __restrict__ w_self,
    const float* __restrict__ w_neigh, const float* __restrict__ bias,
    float* __restrict__ A, int N)
{
  __shared__ float wsT[64][65];
  __shared__ float wnT[64][65];
  const int tid = threadIdx.x, w = tid >> 6, lane = tid & 63;
  for (int idx = tid; idx < 4096; idx += 256) {
    const int o = idx >> 6, i = idx & 63;
    wsT[i][o] = w_self[idx];
    wnT[i][o] = w_neigh[idx];
  }
  __syncthreads();
  for (int n = blockIdx.x * 4 + w; n < N; n += gridDim.x * 4) {
    const int s = rowptr[n], t = rowptr[n + 1];
    float acc = 0.f;
    int j = s;
    for (; j + 4 <= t; j += 4) {
      const int2 p0 = ebin2[j], p1 = ebin2[j + 1], p2 = ebin2[j + 2], p3 = ebin2[j + 3];
      acc += __int_as_float(p0.y) * x[(size_t)p0.x * 64 + lane]
           + __int_as_float(p1.y) * x[(size_t)p1.x * 64 + lane]
           + __int_as_float(p2.y) * x[(size_t)p2.x * 64 + lane]
           + __int_as_float(p3.y) * x[(size_t)p3.x * 64 + lane];
    }
    for (; j < t; j++) {
      const int2 p = ebin2[j];
      acc += __int_as_float(p.y) * x[(size_t)p.x * 64 + lane];
    }
    const float dg = (float)(t - s);
    const float nb = acc / fmaxf(dg, 1.0f);
    const float xv = x[(size_t)n * 64 + lane];
    float a = bias[lane];
#pragma unroll
    for (int i = 0; i < 64; i++)
      a += __shfl(xv, i) * wsT[i][lane] + __shfl(nb, i) * wnT[i][lane];
    a = lrelu(a);
    float ss = a * a;
#pragma unroll
    for (int off = 1; off < 64; off <<= 1) ss += __shfl_xor(ss, off);
    A[(size_t)n * 64 + lane] = a / fmaxf(sqrtf(ss), 1e-12f);
  }
}

// --------- weight conversion: fragment-linear chunk layout (1 KiB chunks) ----
// Region bases (u16): w1 0, w2 16384, w3 49152; chunk = 512 elems = 64 lanes x 8.
// wcat[region + (chunk*64 + lane)*8 + j] = w[sig(t*16 + (lane&15))*K + s*32 + (lane>>4)*8 + j]
__global__ void convert_w(const float* __restrict__ w1, const float* __restrict__ w2,
                          const float* __restrict__ w3,
                          const float* __restrict__ b1, const float* __restrict__ b2,
                          const float* __restrict__ b3, const float* __restrict__ w4,
                          u16* __restrict__ wcat, float* __restrict__ b1p,
                          float* __restrict__ b2p, float* __restrict__ b3p,
                          float* __restrict__ w4p)
{
  const int idx = blockIdx.x * 256 + threadIdx.x;
  if (idx < 57344) {
    const float* w; int K, nsteps, loc;
    if (idx < 16384)      { loc = idx;         w = w1; K = 64;  nsteps = 2; }
    else if (idx < 49152) { loc = idx - 16384; w = w2; K = 256; nsteps = 8; }
    else                  { loc = idx - 49152; w = w3; K = 128; nsteps = 4; }
    const int chunk = loc >> 9;
    const int lane  = (loc >> 3) & 63;
    const int j     = loc & 7;
    const int t = chunk / nsteps, s = chunk % nsteps;
    const int m = sig(t * 16 + (lane & 15));
    const int k = s * 32 + (lane >> 4) * 8 + j;
    wcat[idx] = f2bf(w[m * K + k]);
  }
  if (idx < 256) b1p[idx] = b1[sig(idx)];
  if (idx < 128) b2p[idx] = b2[sig(idx)];
  if (idx < 64)  { b3p[idx] = b3[sig(idx)]; w4p[idx] = w4[sig(idx)]; }
}

extern "C" void kernel_launch(void* const* d_in, const int* in_sizes, int n_in,
                              void* d_out, int out_size, void* d_ws, size_t ws_size,
                              hipStream_t stream)
{
  const float* x       = (const float*)d_in[0];
  const int*   src     = (const int*)d_in[1];
  const int*   dst     = (const int*)d_in[2];
  const float* w1      = (const float*)d_in[3];
  const float* b1      = (const float*)d_in[4];
  const float* w2      = (const float*)d_in[5];
  const float* b2      = (const float*)d_in[6];
  const float* w3      = (const float*)d_in[7];
  const float* b3      = (const float*)d_in[8];
  const float* w4      = (const float*)d_in[9];
  const float* b4      = (const float*)d_in[10];
  const float* w_self  = (const float*)d_in[11];
  const float* w_neigh = (const float*)d_in[12];
  const float* bias    = (const float*)d_in[13];

  const int N = in_sizes[0] / 64;
  const int E = in_sizes[1];

  float* A    = (float*)d_out;                    // [N,64]
  float* eout = (float*)d_out + (size_t)N * 64;   // [E]

  char* ws = (char*)d_ws;
  size_t off = 0;
  auto alloc = [&](size_t bytes) {
    void* p = ws + off;
    off = (off + bytes + 255) & ~(size_t)255;
    return p;
  };
  int*    degi   = (int*)alloc((size_t)N * 4);
  int*    rowptr = (int*)alloc((size_t)(N + 1) * 4);
  int*    cursor = (int*)alloc((size_t)N * 4);
  int*    bsum   = (int*)alloc(1024 * 4);
  int2*   ebin2  = (int2*)alloc((size_t)E * 8);
  short8* wcat   = (short8*)alloc((size_t)57344 * 2);
  float*  b1p    = (float*)alloc(256 * 4);
  float*  b2p    = (float*)alloc(128 * 4);
  float*  b3p    = (float*)alloc(64 * 4);
  float*  w4p    = (float*)alloc(64 * 4);

  hipMemsetAsync(degi, 0, (size_t)N * sizeof(int), stream);

  convert_w<<<224, 256, 0, stream>>>(w1, w2, w3, b1, b2, b3, w4,
                                     (u16*)wcat, b1p, b2p, b3p, w4p);

  deg_hist<<<(E + 255) / 256, 256, 0, stream>>>(dst, degi, E);

  const int nsb = (N + 1023) / 1024;   // <= 256 for N <= 262144
  scan_part<<<nsb, 256, 0, stream>>>(degi, rowptr, bsum, N);
  scan_bsum<<<1, 256, 0, stream>>>(bsum, nsb);
  scan_add<<<nsb, 256, 0, stream>>>(rowptr, bsum, cursor, N, E);

  const int nblk = (E + 255) / 256;    // 256 edges per 512-thread block
  edge_mlp<<<nblk, 512, 0, stream>>>(x, src, dst, wcat, b1p, b2p, b3p, w4p, b4,
                                     rowptr, cursor, ebin2, eout, E);

  node_agg<<<2048, 256, 0, stream>>>(x, rowptr, ebin2, w_self, w_neigh, bias, A, N);
}